// Round 1
// baseline (802.324 us; speedup 1.0000x reference)
//
#include <hip/hip_runtime.h>
#include <cstdint>
#include <cstddef>

#define NPTS 8192
#define DDIM 128
#define BATCH 2
#define BM 64
#define BT 64
#define CSPLIT 4
#define CCH (NPTS / CSPLIT)
#define NROWS (BATCH * NPTS)
#define EPSGAP 1e-3f

// ---------------- y2[b*N+m] = sum_k f1[b,m,k]^2 (one wave per row) -------------
__global__ void y2_kernel(const float* __restrict__ f1, float* __restrict__ y2) {
    int row  = blockIdx.x * 4 + (threadIdx.x >> 6);
    int lane = threadIdx.x & 63;
    const float2* p = reinterpret_cast<const float2*>(f1) + (size_t)row * (DDIM / 2) + lane;
    float2 a = *p;
    float s = fmaf(a.x, a.x, a.y * a.y);
#pragma unroll
    for (int off = 32; off >= 1; off >>= 1) s += __shfl_xor(s, off);
    if (lane == 0) y2[row] = s;
}

// ---------------- main: fp32 tiled GEMM + per-row top-2 argmin -----------------
// Block: 64 rows x 2048 cols scan, 256 threads, 4x4 outputs/thread.
// LDS: row-major float4 tiles with XOR swizzle col' = kc ^ ((r>>2)&7).
__global__ __launch_bounds__(256, 2) void gemm_argmin(
    const float* __restrict__ f0, const float* __restrict__ f1,
    const float* __restrict__ y2g,
    float* __restrict__ bestv, unsigned int* __restrict__ besti,
    float* __restrict__ secondv)
{
    __shared__ float4 As[BM * 32];
    __shared__ float4 Bs[BT * 32];

    const int tid  = threadIdx.x;
    const int tx   = tid & 15;   // col group
    const int ty   = tid >> 4;   // row group
    const int bm   = blockIdx.x;
    const int cs   = blockIdx.y;
    const int b    = blockIdx.z;
    const int row0 = bm * BM;

    const float4* f0v = reinterpret_cast<const float4*>(f0) + ((size_t)b * NPTS + row0) * (DDIM / 4);
    const float4* f1v = reinterpret_cast<const float4*>(f1) + (size_t)b * NPTS * (DDIM / 4);
    const float*  y2b = y2g + b * NPTS;

    // stage A once (64 rows x 128 k)
#pragma unroll
    for (int c = 0; c < 8; ++c) {
        int flat = c * 256 + tid;
        int r = flat >> 5, kc = flat & 31;
        As[r * 32 + (kc ^ ((r >> 2) & 7))] = f0v[(size_t)r * 32 + kc];
    }

    float v1[4], v2[4];
    unsigned int i1[4];
#pragma unroll
    for (int i = 0; i < 4; ++i) { v1[i] = INFINITY; v2[i] = INFINITY; i1[i] = 0u; }

    for (int mt = 0; mt < CCH; mt += BT) {
        const int m0 = cs * CCH + mt;
        __syncthreads();  // protect Bs (prev reads done) and cover A-stage on iter 0
#pragma unroll
        for (int c = 0; c < 8; ++c) {
            int flat = c * 256 + tid;
            int r = flat >> 5, kc = flat & 31;
            Bs[r * 32 + (kc ^ ((r >> 2) & 7))] = f1v[(size_t)(m0 + r) * 32 + kc];
        }
        __syncthreads();

        float acc[4][4];
#pragma unroll
        for (int i = 0; i < 4; ++i)
#pragma unroll
            for (int j = 0; j < 4; ++j) acc[i][j] = 0.0f;

#pragma unroll 4
        for (int kc = 0; kc < 32; ++kc) {
            float4 av[4], bv[4];
#pragma unroll
            for (int i = 0; i < 4; ++i)
                av[i] = As[(ty * 4 + i) * 32 + (kc ^ (ty & 7))];
#pragma unroll
            for (int j = 0; j < 4; ++j)
                bv[j] = Bs[(tx * 4 + j) * 32 + (kc ^ (tx & 7))];
#pragma unroll
            for (int i = 0; i < 4; ++i)
#pragma unroll
                for (int j = 0; j < 4; ++j)
                    acc[i][j] = fmaf(av[i].x, bv[j].x,
                                fmaf(av[i].y, bv[j].y,
                                fmaf(av[i].z, bv[j].z,
                                fmaf(av[i].w, bv[j].w, acc[i][j]))));
        }

        // epilogue: val = y2[m] - 2*dot ; maintain per-row top-2 (first-occurrence)
#pragma unroll
        for (int j = 0; j < 4; ++j) {
            const int m = m0 + tx * 4 + j;
            const float yv = y2b[m];
#pragma unroll
            for (int i = 0; i < 4; ++i) {
                const float v = fmaf(-2.0f, acc[i][j], yv);
                if (v < v1[i]) { v2[i] = v1[i]; v1[i] = v; i1[i] = (unsigned)m; }
                else           { v2[i] = fminf(v2[i], v); }  // v==v1 -> gap 0 -> flagged later
            }
        }
    }

    // reduce top-2 across the 16 tx-lanes sharing each row (butterfly; assoc+comm merge)
#pragma unroll
    for (int i = 0; i < 4; ++i) {
        float a1 = v1[i], a2 = v2[i];
        unsigned int ai = i1[i];
#pragma unroll
        for (int off = 1; off < 16; off <<= 1) {
            float o1 = __shfl_xor(a1, off);
            float o2 = __shfl_xor(a2, off);
            unsigned int oi = __shfl_xor(ai, off);
            if (o1 < a1 || (o1 == a1 && oi < ai)) { a2 = fminf(a1, o2); a1 = o1; ai = oi; }
            else                                  { a2 = fminf(a2, fminf(o1, o2)); }
        }
        if (tx == 0) {
            const int gr = b * NPTS + row0 + ty * 4 + i;
            bestv[cs * NROWS + gr]   = a1;
            besti[cs * NROWS + gr]   = ai;
            secondv[cs * NROWS + gr] = a2;
        }
    }
}

// ---------------- merge the CSPLIT partials, flag near-ties --------------------
__global__ void resolve_kernel(const float* __restrict__ bestv,
                               const unsigned int* __restrict__ besti,
                               const float* __restrict__ secondv,
                               unsigned int* __restrict__ idxFinal,
                               unsigned int* __restrict__ flags)
{
    const int gr = blockIdx.x * 256 + threadIdx.x;
    float a1 = INFINITY, a2 = INFINITY;
    unsigned int ai = 0u;
#pragma unroll
    for (int cs = 0; cs < CSPLIT; ++cs) {
        const float o1 = bestv[cs * NROWS + gr];
        const float o2 = secondv[cs * NROWS + gr];
        const unsigned int oi = besti[cs * NROWS + gr];
        if (o1 < a1 || (o1 == a1 && oi < ai)) { a2 = fminf(a1, o2); a1 = o1; ai = oi; }
        else                                  { a2 = fminf(a2, fminf(o1, o2)); }
    }
    idxFinal[gr] = ai;
    flags[gr] = (a2 - a1 < EPSGAP) ? 1u : 0u;
}

// ---------------- fp64 exact recheck for flagged rows --------------------------
__global__ __launch_bounds__(256) void recheck_kernel(
    const float* __restrict__ f0, const float* __restrict__ f1,
    const unsigned int* __restrict__ flags, unsigned int* __restrict__ idxFinal)
{
    const int gr = blockIdx.x;
    if (flags[gr] == 0u) return;
    const int b = gr >> 13, n = gr & (NPTS - 1);
    __shared__ float xrow[DDIM];
    __shared__ double redv[256];
    __shared__ unsigned int redi[256];
    const int tid = threadIdx.x;
    if (tid < DDIM) xrow[tid] = f0[((size_t)b * NPTS + n) * DDIM + tid];
    __syncthreads();
    double bv = 1e300;
    unsigned int bi = 0xFFFFFFFFu;
    for (int m = tid; m < NPTS; m += 256) {
        const float* yp = f1 + ((size_t)b * NPTS + m) * DDIM;
        double dsum = 0.0;
        for (int k = 0; k < DDIM; ++k) {
            const double xv = (double)xrow[k];
            const double yv = (double)yp[k];
            dsum += yv * yv - 2.0 * xv * yv;
        }
        if (dsum < bv || (dsum == bv && (unsigned)m < bi)) { bv = dsum; bi = (unsigned)m; }
    }
    redv[tid] = bv; redi[tid] = bi;
    __syncthreads();
    for (int s = 128; s >= 1; s >>= 1) {
        if (tid < s) {
            const double ov = redv[tid + s]; const unsigned int oi = redi[tid + s];
            if (ov < redv[tid] || (ov == redv[tid] && oi < redi[tid])) { redv[tid] = ov; redi[tid] = oi; }
        }
        __syncthreads();
    }
    if (tid == 0) idxFinal[gr] = redi[0];
}

// ---------------- write one-hot 1.0s and idx-as-float tail ---------------------
__global__ void scatter_kernel(const unsigned int* __restrict__ idxFinal, float* __restrict__ out) {
    const int gr = blockIdx.x * 256 + threadIdx.x;
    const unsigned int idx = idxFinal[gr];
    out[(size_t)gr * NPTS + idx] = 1.0f;
    out[(size_t)BATCH * NPTS * NPTS + gr] = (float)idx;
}

extern "C" void kernel_launch(void* const* d_in, const int* in_sizes, int n_in,
                              void* d_out, int out_size, void* d_ws, size_t ws_size,
                              hipStream_t stream)
{
    const float* f0 = (const float*)d_in[0];
    const float* f1 = (const float*)d_in[1];
    float* out = (float*)d_out;

    // ws layout (floats): y2[NROWS] | bestv[4*NROWS] | secondv[4*NROWS] |
    //                     besti[4*NROWS] | idxFinal[NROWS] | flags[NROWS]  (~0.94 MB)
    float* ws = (float*)d_ws;
    float* y2      = ws;
    float* bestv   = ws + NROWS;
    float* secondv = bestv + CSPLIT * NROWS;
    unsigned int* besti    = (unsigned int*)(secondv + CSPLIT * NROWS);
    unsigned int* idxFinal = besti + CSPLIT * NROWS;
    unsigned int* flags    = idxFinal + NROWS;

    hipMemsetAsync(d_out, 0, (size_t)out_size * sizeof(float), stream);

    y2_kernel<<<NROWS / 4, 256, 0, stream>>>(f1, y2);
    gemm_argmin<<<dim3(NPTS / BM, CSPLIT, BATCH), 256, 0, stream>>>(f0, f1, y2, bestv, besti, secondv);
    resolve_kernel<<<NROWS / 256, 256, 0, stream>>>(bestv, besti, secondv, idxFinal, flags);
    recheck_kernel<<<NROWS, 256, 0, stream>>>(f0, f1, flags, idxFinal);
    scatter_kernel<<<NROWS / 256, 256, 0, stream>>>(idxFinal, out);
}

// Round 2
// 711.716 us; speedup vs baseline: 1.1273x; 1.1273x over previous
//
#include <hip/hip_runtime.h>
#include <cstdint>
#include <cstddef>

#define NPTS 8192
#define DDIM 128
#define BATCH 2
#define NROWS (BATCH * NPTS)
#define EPSGAP 0.05f
#define NCOLT 64   // 8192 / 128 column tiles (partials per row)

typedef __attribute__((ext_vector_type(8))) short short8v;
typedef __attribute__((ext_vector_type(4))) float f32x4;

typedef __attribute__((address_space(3))) unsigned int as3_uint;
typedef const __attribute__((address_space(1))) unsigned int as1_uint;

static __device__ __forceinline__ unsigned short f2bf_rne(float x) {
    unsigned int u = __float_as_uint(x);
    unsigned int r = (u + 0x7FFFu + ((u >> 16) & 1u)) >> 16;
    return (unsigned short)r;
}
static __device__ __forceinline__ float bf2f(unsigned short h) {
    return __uint_as_float(((unsigned int)h) << 16);
}

// ---- split fp32 -> [xh(128) | xl(128)] bf16 rows (K_ext = 256) ---------------
__global__ void split_kernel(const float* __restrict__ src, unsigned short* __restrict__ dst) {
    size_t t = (size_t)blockIdx.x * 256 + threadIdx.x;   // one per 4 elems
    size_t row = t >> 5;
    int kc = (int)(t & 31) * 4;
    float4 v = reinterpret_cast<const float4*>(src)[t];
    float xs[4] = {v.x, v.y, v.z, v.w};
    ushort4 h, l;
    unsigned short hh[4], ll[4];
#pragma unroll
    for (int e = 0; e < 4; ++e) {
        float x = xs[e];
        unsigned short hb = f2bf_rne(x);
        float lo = x - bf2f(hb);
        hh[e] = hb; ll[e] = f2bf_rne(lo);
    }
    h.x = hh[0]; h.y = hh[1]; h.z = hh[2]; h.w = hh[3];
    l.x = ll[0]; l.y = ll[1]; l.z = ll[2]; l.w = ll[3];
    *reinterpret_cast<ushort4*>(&dst[row * 256 + kc])       = h;
    *reinterpret_cast<ushort4*>(&dst[row * 256 + 128 + kc]) = l;
}

// ---- y2[b*N+m] = sum_k f1[b,m,k]^2 (fp32 exact-ish, one wave per row) --------
__global__ void y2_kernel(const float* __restrict__ f1, float* __restrict__ y2) {
    int row  = blockIdx.x * 4 + (threadIdx.x >> 6);
    int lane = threadIdx.x & 63;
    const float2* p = reinterpret_cast<const float2*>(f1) + (size_t)row * (DDIM / 2) + lane;
    float2 a = *p;
    float s = fmaf(a.x, a.x, a.y * a.y);
#pragma unroll
    for (int off = 32; off >= 1; off >>= 1) s += __shfl_xor(s, off);
    if (lane == 0) y2[row] = s;
}

// ---- MFMA GEMM (K=384 emulating fp32 via bf16 hi/lo) + top-2 argmin epilogue --
// 128x128 tile, 4 waves (2x2), each wave 64x64 via 4x4 mfma_f32_16x16x32_bf16.
// LDS tiles [128][64] bf16, XOR-swizzled chunks: slot(r,kc) holds src chunk kc^(r&7).
__global__ __launch_bounds__(256) void gemm_mfma(
    const unsigned short* __restrict__ Aext,  // [B][N][256] = [xh|xl]
    const unsigned short* __restrict__ Bext,
    const float* __restrict__ y2g,
    float* __restrict__ pv1, float* __restrict__ pv2, unsigned int* __restrict__ pidx)
{
    __shared__ short As[128 * 64];
    __shared__ short Bs[128 * 64];
    __shared__ float rv1[2][128];
    __shared__ float rv2[2][128];
    __shared__ unsigned int ri[2][128];

    const int tid  = threadIdx.x;
    const int lane = tid & 63;
    const int wid  = tid >> 6;
    const int wr   = wid >> 1, wc = wid & 1;
    const int l15  = lane & 15, l4 = lane >> 4;
    const int bm   = blockIdx.x;   // row tile
    const int bnc  = blockIdx.y;   // col tile
    const int b    = blockIdx.z;
    const int row0 = bm * 128, col0 = bnc * 128;

    const unsigned short* Abase = Aext + ((size_t)b * NPTS + row0) * 256;
    const unsigned short* Bbase = Bext + ((size_t)b * NPTS + col0) * 256;

    f32x4 acc[4][4];
#pragma unroll
    for (int i = 0; i < 4; ++i)
#pragma unroll
        for (int j = 0; j < 4; ++j) acc[i][j] = (f32x4)0.0f;

    // dot3 = xh.yh + xh.yl + xl.yh as K=384: A chunks [h,h,l? ...] per table
    const int akoff[6] = {0, 64, 128, 192, 0, 64};   // xh,xh,xl,xl,xh,xh
    const int bkoff[6] = {0, 64, 0, 64, 128, 192};   // yh,yh,yh,yh,yl,yl

#pragma unroll
    for (int kk = 0; kk < 6; ++kk) {
        __syncthreads();   // prev-iteration LDS reads complete
        {
            const int ka = akoff[kk], kb = bkoff[kk];
#pragma unroll
            for (int it = 0; it < 4; ++it) {
                int flat = it * 256 + tid;          // 16B-chunk id 0..1023
                int r = flat >> 3, kc = flat & 7;
                int kcs = kc ^ (r & 7);             // inverse-swizzled source chunk
                const unsigned short* ga = Abase + (size_t)r * 256 + ka + kcs * 8;
                const unsigned short* gb = Bbase + (size_t)r * 256 + kb + kcs * 8;
                __builtin_amdgcn_global_load_lds((as1_uint*)ga, (as3_uint*)&As[flat * 8], 16, 0, 0);
                __builtin_amdgcn_global_load_lds((as1_uint*)gb, (as3_uint*)&Bs[flat * 8], 16, 0, 0);
            }
        }
        __syncthreads();   // staged data visible
#pragma unroll
        for (int ks = 0; ks < 2; ++ks) {
            short8v a[4], bf[4];
#pragma unroll
            for (int i = 0; i < 4; ++i) {
                int ra = wr * 64 + i * 16 + l15;
                int ch = ks * 4 + l4;
                a[i] = *reinterpret_cast<const short8v*>(&As[ra * 64 + ((ch ^ (ra & 7)) << 3)]);
            }
#pragma unroll
            for (int j = 0; j < 4; ++j) {
                int rb = wc * 64 + j * 16 + l15;
                int ch = ks * 4 + l4;
                bf[j] = *reinterpret_cast<const short8v*>(&Bs[rb * 64 + ((ch ^ (rb & 7)) << 3)]);
            }
#pragma unroll
            for (int i = 0; i < 4; ++i)
#pragma unroll
                for (int j = 0; j < 4; ++j)
                    acc[i][j] = __builtin_amdgcn_mfma_f32_16x16x32_bf16(a[i], bf[j], acc[i][j], 0, 0, 0);
        }
    }

    // epilogue: v = y2[m] - 2*dot ; per-row top-2 over this wave's 64 cols
    const float* y2b = y2g + b * NPTS;
    float yv[4];
#pragma unroll
    for (int j = 0; j < 4; ++j) yv[j] = y2b[col0 + wc * 64 + j * 16 + l15];

#pragma unroll
    for (int i = 0; i < 4; ++i) {
#pragma unroll
        for (int q = 0; q < 4; ++q) {
            float v1 = INFINITY, v2 = INFINITY;
            unsigned int mi = 0u;
#pragma unroll
            for (int j = 0; j < 4; ++j) {
                const float v = fmaf(-2.0f, acc[i][j][q], yv[j]);
                const unsigned int m = (unsigned)(col0 + wc * 64 + j * 16 + l15);
                if (v < v1) { v2 = v1; v1 = v; mi = m; }
                else        { v2 = fminf(v2, v); }
            }
#pragma unroll
            for (int off = 1; off < 16; off <<= 1) {
                float o1 = __shfl_xor(v1, off);
                float o2 = __shfl_xor(v2, off);
                unsigned int oi = __shfl_xor(mi, off);
                if (o1 < v1 || (o1 == v1 && oi < mi)) { v2 = fminf(v1, o2); v1 = o1; mi = oi; }
                else                                  { v2 = fminf(v2, fminf(o1, o2)); }
            }
            if (l15 == 0) {
                const int rl = wr * 64 + i * 16 + l4 * 4 + q;
                rv1[wc][rl] = v1; rv2[wc][rl] = v2; ri[wc][rl] = mi;
            }
        }
    }
    __syncthreads();
    if (tid < 128) {
        float a1 = rv1[0][tid], a2 = rv2[0][tid];
        unsigned int ai = ri[0][tid];
        const float o1 = rv1[1][tid], o2 = rv2[1][tid];
        const unsigned int oi = ri[1][tid];
        if (o1 < a1 || (o1 == a1 && oi < ai)) { a2 = fminf(a1, o2); a1 = o1; ai = oi; }
        else                                  { a2 = fminf(a2, fminf(o1, o2)); }
        const size_t gr = (size_t)b * NPTS + row0 + tid;
        pv1[(size_t)bnc * NROWS + gr] = a1;
        pv2[(size_t)bnc * NROWS + gr] = a2;
        pidx[(size_t)bnc * NROWS + gr] = ai;
    }
}

// ---- merge the 64 column-tile partials, flag near-ties ------------------------
__global__ void resolve_kernel(const float* __restrict__ pv1, const float* __restrict__ pv2,
                               const unsigned int* __restrict__ pidx,
                               unsigned int* __restrict__ idxFinal, unsigned int* __restrict__ flags)
{
    const int gr = blockIdx.x * 256 + threadIdx.x;
    float a1 = INFINITY, a2 = INFINITY;
    unsigned int ai = 0u;
    for (int cs = 0; cs < NCOLT; ++cs) {
        const float o1 = pv1[(size_t)cs * NROWS + gr];
        const float o2 = pv2[(size_t)cs * NROWS + gr];
        const unsigned int oi = pidx[(size_t)cs * NROWS + gr];
        if (o1 < a1 || (o1 == a1 && oi < ai)) { a2 = fminf(a1, o2); a1 = o1; ai = oi; }
        else                                  { a2 = fminf(a2, fminf(o1, o2)); }
    }
    idxFinal[gr] = ai;
    flags[gr] = (a2 - a1 < EPSGAP) ? 1u : 0u;
}

// ---- fp64 exact recheck for flagged rows --------------------------------------
__global__ __launch_bounds__(256) void recheck_kernel(
    const float* __restrict__ f0, const float* __restrict__ f1,
    const unsigned int* __restrict__ flags, unsigned int* __restrict__ idxFinal)
{
    const int gr = blockIdx.x;
    if (flags[gr] == 0u) return;
    const int b = gr >> 13, n = gr & (NPTS - 1);
    __shared__ float xrow[DDIM];
    __shared__ double redv[256];
    __shared__ unsigned int redi[256];
    const int tid = threadIdx.x;
    if (tid < DDIM) xrow[tid] = f0[((size_t)b * NPTS + n) * DDIM + tid];
    __syncthreads();
    double bv = 1e300;
    unsigned int bi = 0xFFFFFFFFu;
    for (int m = tid; m < NPTS; m += 256) {
        const float* yp = f1 + ((size_t)b * NPTS + m) * DDIM;
        double dsum = 0.0;
        for (int k = 0; k < DDIM; ++k) {
            const double xv = (double)xrow[k];
            const double yv = (double)yp[k];
            dsum += yv * yv - 2.0 * xv * yv;
        }
        if (dsum < bv || (dsum == bv && (unsigned)m < bi)) { bv = dsum; bi = (unsigned)m; }
    }
    redv[tid] = bv; redi[tid] = bi;
    __syncthreads();
    for (int s = 128; s >= 1; s >>= 1) {
        if (tid < s) {
            const double ov = redv[tid + s]; const unsigned int oi = redi[tid + s];
            if (ov < redv[tid] || (ov == redv[tid] && oi < redi[tid])) { redv[tid] = ov; redi[tid] = oi; }
        }
        __syncthreads();
    }
    if (tid == 0) idxFinal[gr] = redi[0];
}

// ---- write one-hot 1.0s and idx-as-float tail ---------------------------------
__global__ void scatter_kernel(const unsigned int* __restrict__ idxFinal, float* __restrict__ out) {
    const int gr = blockIdx.x * 256 + threadIdx.x;
    const unsigned int idx = idxFinal[gr];
    out[(size_t)gr * NPTS + idx] = 1.0f;
    out[(size_t)BATCH * NPTS * NPTS + gr] = (float)idx;
}

extern "C" void kernel_launch(void* const* d_in, const int* in_sizes, int n_in,
                              void* d_out, int out_size, void* d_ws, size_t ws_size,
                              hipStream_t stream)
{
    const float* f0 = (const float*)d_in[0];
    const float* f1 = (const float*)d_in[1];
    float* out = (float*)d_out;

    // ws layout (bytes):
    // Aext bf16 [2][8192][256]  : 8,388,608
    // Bext bf16 [2][8192][256]  : 8,388,608
    // y2   f32  [NROWS]         :    65,536
    // pv1  f32  [64][NROWS]     : 4,194,304
    // pv2  f32  [64][NROWS]     : 4,194,304
    // pidx u32  [64][NROWS]     : 4,194,304
    // idxFinal u32 [NROWS]      :    65,536
    // flags    u32 [NROWS]      :    65,536   (total ~29.6 MB)
    char* wsb = (char*)d_ws;
    unsigned short* Aext = (unsigned short*)wsb;                  wsb += (size_t)BATCH * NPTS * 256 * 2;
    unsigned short* Bext = (unsigned short*)wsb;                  wsb += (size_t)BATCH * NPTS * 256 * 2;
    float* y2            = (float*)wsb;                           wsb += (size_t)NROWS * 4;
    float* pv1           = (float*)wsb;                           wsb += (size_t)NCOLT * NROWS * 4;
    float* pv2           = (float*)wsb;                           wsb += (size_t)NCOLT * NROWS * 4;
    unsigned int* pidx   = (unsigned int*)wsb;                    wsb += (size_t)NCOLT * NROWS * 4;
    unsigned int* idxFinal = (unsigned int*)wsb;                  wsb += (size_t)NROWS * 4;
    unsigned int* flags    = (unsigned int*)wsb;

    hipMemsetAsync(d_out, 0, (size_t)out_size * sizeof(float), stream);

    split_kernel<<<(BATCH * NPTS * 32) / 256, 256, 0, stream>>>(f0, Aext);
    split_kernel<<<(BATCH * NPTS * 32) / 256, 256, 0, stream>>>(f1, Bext);
    y2_kernel<<<NROWS / 4, 256, 0, stream>>>(f1, y2);
    gemm_mfma<<<dim3(NPTS / 128, NPTS / 128, BATCH), 256, 0, stream>>>(Aext, Bext, y2, pv1, pv2, pidx);
    resolve_kernel<<<NROWS / 256, 256, 0, stream>>>(pv1, pv2, pidx, idxFinal, flags);
    recheck_kernel<<<NROWS, 256, 0, stream>>>(f0, f1, flags, idxFinal);
    scatter_kernel<<<NROWS / 256, 256, 0, stream>>>(idxFinal, out);
}

// Round 3
// 333.324 us; speedup vs baseline: 2.4070x; 2.1352x over previous
//
#include <hip/hip_runtime.h>
#include <cstdint>
#include <cstddef>

#define NPTS 8192
#define DDIM 128
#define BATCH 2
#define NROWS (BATCH * NPTS)
#define EPSGAP 0.02f
#define NCOLT 64   // 8192 / 128 column tiles (partials per row)
#define RCAP 2048  // candidate-list capacity in recheck

typedef __attribute__((ext_vector_type(8))) short short8v;
typedef __attribute__((ext_vector_type(4))) float f32x4;

typedef __attribute__((address_space(3))) unsigned int as3_uint;
typedef const __attribute__((address_space(1))) unsigned int as1_uint;

static __device__ __forceinline__ unsigned short f2bf_rne(float x) {
    unsigned int u = __float_as_uint(x);
    unsigned int r = (u + 0x7FFFu + ((u >> 16) & 1u)) >> 16;
    return (unsigned short)r;
}
static __device__ __forceinline__ float bf2f(unsigned short h) {
    return __uint_as_float(((unsigned int)h) << 16);
}

// ---- split fp32 -> [xh(128) | xl(128)] bf16 rows (K_ext = 256) ---------------
__global__ void split_kernel(const float* __restrict__ src, unsigned short* __restrict__ dst) {
    size_t t = (size_t)blockIdx.x * 256 + threadIdx.x;   // one per 4 elems
    size_t row = t >> 5;
    int kc = (int)(t & 31) * 4;
    float4 v = reinterpret_cast<const float4*>(src)[t];
    float xs[4] = {v.x, v.y, v.z, v.w};
    ushort4 h, l;
    unsigned short hh[4], ll[4];
#pragma unroll
    for (int e = 0; e < 4; ++e) {
        float x = xs[e];
        unsigned short hb = f2bf_rne(x);
        float lo = x - bf2f(hb);
        hh[e] = hb; ll[e] = f2bf_rne(lo);
    }
    h.x = hh[0]; h.y = hh[1]; h.z = hh[2]; h.w = hh[3];
    l.x = ll[0]; l.y = ll[1]; l.z = ll[2]; l.w = ll[3];
    *reinterpret_cast<ushort4*>(&dst[row * 256 + kc])       = h;
    *reinterpret_cast<ushort4*>(&dst[row * 256 + 128 + kc]) = l;
}

// ---- y2[b*N+m] = sum_k f1[b,m,k]^2 (one wave per row) -------------------------
__global__ void y2_kernel(const float* __restrict__ f1, float* __restrict__ y2) {
    int row  = blockIdx.x * 4 + (threadIdx.x >> 6);
    int lane = threadIdx.x & 63;
    const float2* p = reinterpret_cast<const float2*>(f1) + (size_t)row * (DDIM / 2) + lane;
    float2 a = *p;
    float s = fmaf(a.x, a.x, a.y * a.y);
#pragma unroll
    for (int off = 32; off >= 1; off >>= 1) s += __shfl_xor(s, off);
    if (lane == 0) y2[row] = s;
}

// ---- MFMA GEMM (K=384 emulating fp32 via bf16 hi/lo) + top-2 argmin epilogue --
__global__ __launch_bounds__(256) void gemm_mfma(
    const unsigned short* __restrict__ Aext,  // [B][N][256] = [xh|xl]
    const unsigned short* __restrict__ Bext,
    const float* __restrict__ y2g,
    float* __restrict__ pv1, float* __restrict__ pv2, unsigned int* __restrict__ pidx)
{
    __shared__ short As[128 * 64];
    __shared__ short Bs[128 * 64];
    __shared__ float rv1[2][128];
    __shared__ float rv2[2][128];
    __shared__ unsigned int ri[2][128];

    const int tid  = threadIdx.x;
    const int lane = tid & 63;
    const int wid  = tid >> 6;
    const int wr   = wid >> 1, wc = wid & 1;
    const int l15  = lane & 15, l4 = lane >> 4;
    const int bm   = blockIdx.x;
    const int bnc  = blockIdx.y;
    const int b    = blockIdx.z;
    const int row0 = bm * 128, col0 = bnc * 128;

    const unsigned short* Abase = Aext + ((size_t)b * NPTS + row0) * 256;
    const unsigned short* Bbase = Bext + ((size_t)b * NPTS + col0) * 256;

    f32x4 acc[4][4];
#pragma unroll
    for (int i = 0; i < 4; ++i)
#pragma unroll
        for (int j = 0; j < 4; ++j) acc[i][j] = (f32x4)0.0f;

    const int akoff[6] = {0, 64, 128, 192, 0, 64};   // xh,xh,xl,xl,xh,xh
    const int bkoff[6] = {0, 64, 0, 64, 128, 192};   // yh,yh,yh,yh,yl,yl

#pragma unroll
    for (int kk = 0; kk < 6; ++kk) {
        __syncthreads();
        {
            const int ka = akoff[kk], kb = bkoff[kk];
#pragma unroll
            for (int it = 0; it < 4; ++it) {
                int flat = it * 256 + tid;
                int r = flat >> 3, kc = flat & 7;
                int kcs = kc ^ (r & 7);
                const unsigned short* ga = Abase + (size_t)r * 256 + ka + kcs * 8;
                const unsigned short* gb = Bbase + (size_t)r * 256 + kb + kcs * 8;
                __builtin_amdgcn_global_load_lds((as1_uint*)ga, (as3_uint*)&As[flat * 8], 16, 0, 0);
                __builtin_amdgcn_global_load_lds((as1_uint*)gb, (as3_uint*)&Bs[flat * 8], 16, 0, 0);
            }
        }
        __syncthreads();
#pragma unroll
        for (int ks = 0; ks < 2; ++ks) {
            short8v a[4], bf[4];
#pragma unroll
            for (int i = 0; i < 4; ++i) {
                int ra = wr * 64 + i * 16 + l15;
                int ch = ks * 4 + l4;
                a[i] = *reinterpret_cast<const short8v*>(&As[ra * 64 + ((ch ^ (ra & 7)) << 3)]);
            }
#pragma unroll
            for (int j = 0; j < 4; ++j) {
                int rb = wc * 64 + j * 16 + l15;
                int ch = ks * 4 + l4;
                bf[j] = *reinterpret_cast<const short8v*>(&Bs[rb * 64 + ((ch ^ (rb & 7)) << 3)]);
            }
#pragma unroll
            for (int i = 0; i < 4; ++i)
#pragma unroll
                for (int j = 0; j < 4; ++j)
                    acc[i][j] = __builtin_amdgcn_mfma_f32_16x16x32_bf16(a[i], bf[j], acc[i][j], 0, 0, 0);
        }
    }

    const float* y2b = y2g + b * NPTS;
    float yv[4];
#pragma unroll
    for (int j = 0; j < 4; ++j) yv[j] = y2b[col0 + wc * 64 + j * 16 + l15];

#pragma unroll
    for (int i = 0; i < 4; ++i) {
#pragma unroll
        for (int q = 0; q < 4; ++q) {
            float v1 = INFINITY, v2 = INFINITY;
            unsigned int mi = 0u;
#pragma unroll
            for (int j = 0; j < 4; ++j) {
                const float v = fmaf(-2.0f, acc[i][j][q], yv[j]);
                const unsigned int m = (unsigned)(col0 + wc * 64 + j * 16 + l15);
                if (v < v1) { v2 = v1; v1 = v; mi = m; }
                else        { v2 = fminf(v2, v); }
            }
#pragma unroll
            for (int off = 1; off < 16; off <<= 1) {
                float o1 = __shfl_xor(v1, off);
                float o2 = __shfl_xor(v2, off);
                unsigned int oi = __shfl_xor(mi, off);
                if (o1 < v1 || (o1 == v1 && oi < mi)) { v2 = fminf(v1, o2); v1 = o1; mi = oi; }
                else                                  { v2 = fminf(v2, fminf(o1, o2)); }
            }
            if (l15 == 0) {
                const int rl = wr * 64 + i * 16 + l4 * 4 + q;
                rv1[wc][rl] = v1; rv2[wc][rl] = v2; ri[wc][rl] = mi;
            }
        }
    }
    __syncthreads();
    if (tid < 128) {
        float a1 = rv1[0][tid], a2 = rv2[0][tid];
        unsigned int ai = ri[0][tid];
        const float o1 = rv1[1][tid], o2 = rv2[1][tid];
        const unsigned int oi = ri[1][tid];
        if (o1 < a1 || (o1 == a1 && oi < ai)) { a2 = fminf(a1, o2); a1 = o1; ai = oi; }
        else                                  { a2 = fminf(a2, fminf(o1, o2)); }
        const size_t gr = (size_t)b * NPTS + row0 + tid;
        pv1[(size_t)bnc * NROWS + gr] = a1;
        pv2[(size_t)bnc * NROWS + gr] = a2;
        pidx[(size_t)bnc * NROWS + gr] = ai;
    }
}

// ---- merge the 64 column-tile partials; compact near-tie rows into a list -----
__global__ void resolve_kernel(const float* __restrict__ pv1, const float* __restrict__ pv2,
                               const unsigned int* __restrict__ pidx,
                               unsigned int* __restrict__ idxFinal, float* __restrict__ bestval,
                               unsigned int* __restrict__ flagList, unsigned int* __restrict__ flagCount)
{
    const int gr = blockIdx.x * 256 + threadIdx.x;
    float a1 = INFINITY, a2 = INFINITY;
    unsigned int ai = 0u;
    for (int cs = 0; cs < NCOLT; ++cs) {
        const float o1 = pv1[(size_t)cs * NROWS + gr];
        const float o2 = pv2[(size_t)cs * NROWS + gr];
        const unsigned int oi = pidx[(size_t)cs * NROWS + gr];
        if (o1 < a1 || (o1 == a1 && oi < ai)) { a2 = fminf(a1, o2); a1 = o1; ai = oi; }
        else                                  { a2 = fminf(a2, fminf(o1, o2)); }
    }
    idxFinal[gr] = ai;
    bestval[gr] = a1;
    if (a2 - a1 < EPSGAP) {
        unsigned int pos = atomicAdd(flagCount, 1u);
        flagList[pos] = (unsigned int)gr;
    }
}

// ---- candidate-window fp64 recheck (fixed grid, grid-strides the flag list) ---
// For a flagged row: only candidates with approx val <= bestval+EPSGAP can win.
// Tiles are screened via their stored top-2; typical row -> ~2 exact fp64 dots.
__global__ __launch_bounds__(256) void recheck_kernel(
    const float* __restrict__ f0, const float* __restrict__ f1,
    const float* __restrict__ pv1, const float* __restrict__ pv2,
    const unsigned int* __restrict__ pidx, const float* __restrict__ bestval,
    const unsigned int* __restrict__ flagList, const unsigned int* __restrict__ flagCount,
    unsigned int* __restrict__ idxFinal)
{
    __shared__ float xrow[DDIM];
    __shared__ unsigned int cand[RCAP];
    __shared__ int ncand;
    __shared__ double redv[256];
    __shared__ unsigned int redi[256];

    const int tid = threadIdx.x;
    const unsigned int nflag = *flagCount;

    for (unsigned int li = blockIdx.x; li < nflag; li += gridDim.x) {
        const int gr = (int)flagList[li];
        const int b = gr >> 13, n = gr & (NPTS - 1);
        const float W = bestval[gr] + EPSGAP;

        if (tid == 0) ncand = 0;
        if (tid < DDIM) xrow[tid] = f0[((size_t)b * NPTS + n) * DDIM + tid];
        __syncthreads();

        // screen the 64 tiles
        if (tid < NCOLT) {
            const size_t base = (size_t)tid * NROWS + gr;
            const float t1 = pv1[base];
            if (t1 <= W) {
                if (pv2[base] <= W) {
                    int p = atomicAdd(&ncand, 128);
                    if (p + 128 <= RCAP)
                        for (int c = 0; c < 128; ++c) cand[p + c] = (unsigned)(tid * 128 + c);
                } else {
                    int p = atomicAdd(&ncand, 1);
                    if (p < RCAP) cand[p] = pidx[base];
                }
            }
        }
        __syncthreads();

        const int nc = ncand;
        double bv = 1e300;
        unsigned int bi = 0xFFFFFFFFu;
        if (nc <= RCAP) {
            for (int c = tid; c < nc; c += 256) {
                const unsigned int m = cand[c];
                const float4* ypv = reinterpret_cast<const float4*>(f1 + ((size_t)b * NPTS + m) * DDIM);
                const float4* xpv = reinterpret_cast<const float4*>(xrow);
                double s0 = 0.0, s1 = 0.0, s2 = 0.0, s3 = 0.0;
#pragma unroll 8
                for (int k4 = 0; k4 < DDIM / 4; ++k4) {
                    const float4 y = ypv[k4];
                    const float4 x = xpv[k4];
                    s0 = fma((double)y.x, (double)y.x - 2.0 * (double)x.x, s0);
                    s1 = fma((double)y.y, (double)y.y - 2.0 * (double)x.y, s1);
                    s2 = fma((double)y.z, (double)y.z - 2.0 * (double)x.z, s2);
                    s3 = fma((double)y.w, (double)y.w - 2.0 * (double)x.w, s3);
                }
                const double v = (s0 + s1) + (s2 + s3);
                if (v < bv || (v == bv && m < bi)) { bv = v; bi = m; }
            }
        } else {
            // overflow fallback: full fp64 row scan
            for (int m = tid; m < NPTS; m += 256) {
                const float4* ypv = reinterpret_cast<const float4*>(f1 + ((size_t)b * NPTS + m) * DDIM);
                const float4* xpv = reinterpret_cast<const float4*>(xrow);
                double s0 = 0.0, s1 = 0.0, s2 = 0.0, s3 = 0.0;
#pragma unroll 4
                for (int k4 = 0; k4 < DDIM / 4; ++k4) {
                    const float4 y = ypv[k4];
                    const float4 x = xpv[k4];
                    s0 = fma((double)y.x, (double)y.x - 2.0 * (double)x.x, s0);
                    s1 = fma((double)y.y, (double)y.y - 2.0 * (double)x.y, s1);
                    s2 = fma((double)y.z, (double)y.z - 2.0 * (double)x.z, s2);
                    s3 = fma((double)y.w, (double)y.w - 2.0 * (double)x.w, s3);
                }
                const double v = (s0 + s1) + (s2 + s3);
                if (v < bv || (v == bv && (unsigned)m < bi)) { bv = v; bi = (unsigned)m; }
            }
        }
        redv[tid] = bv; redi[tid] = bi;
        __syncthreads();
        for (int s = 128; s >= 1; s >>= 1) {
            if (tid < s) {
                const double ov = redv[tid + s]; const unsigned int oi = redi[tid + s];
                if (ov < redv[tid] || (ov == redv[tid] && oi < redi[tid])) { redv[tid] = ov; redi[tid] = oi; }
            }
            __syncthreads();
        }
        if (tid == 0) idxFinal[gr] = redi[0];
        __syncthreads();   // protect shared reuse on next list iteration
    }
}

// ---- write one-hot 1.0s and idx-as-float tail ---------------------------------
__global__ void scatter_kernel(const unsigned int* __restrict__ idxFinal, float* __restrict__ out) {
    const int gr = blockIdx.x * 256 + threadIdx.x;
    const unsigned int idx = idxFinal[gr];
    out[(size_t)gr * NPTS + idx] = 1.0f;
    out[(size_t)BATCH * NPTS * NPTS + gr] = (float)idx;
}

extern "C" void kernel_launch(void* const* d_in, const int* in_sizes, int n_in,
                              void* d_out, int out_size, void* d_ws, size_t ws_size,
                              hipStream_t stream)
{
    const float* f0 = (const float*)d_in[0];
    const float* f1 = (const float*)d_in[1];
    float* out = (float*)d_out;

    // ws layout (bytes): Aext 8.39M | Bext 8.39M | y2 64K | pv1 4.19M | pv2 4.19M
    //                    | pidx 4.19M | idxFinal 64K | bestval 64K | flagList 64K
    //                    | flagCount 4  (~29.8 MB)
    char* wsb = (char*)d_ws;
    unsigned short* Aext = (unsigned short*)wsb;                  wsb += (size_t)BATCH * NPTS * 256 * 2;
    unsigned short* Bext = (unsigned short*)wsb;                  wsb += (size_t)BATCH * NPTS * 256 * 2;
    float* y2            = (float*)wsb;                           wsb += (size_t)NROWS * 4;
    float* pv1           = (float*)wsb;                           wsb += (size_t)NCOLT * NROWS * 4;
    float* pv2           = (float*)wsb;                           wsb += (size_t)NCOLT * NROWS * 4;
    unsigned int* pidx   = (unsigned int*)wsb;                    wsb += (size_t)NCOLT * NROWS * 4;
    unsigned int* idxFinal = (unsigned int*)wsb;                  wsb += (size_t)NROWS * 4;
    float* bestval       = (float*)wsb;                           wsb += (size_t)NROWS * 4;
    unsigned int* flagList = (unsigned int*)wsb;                  wsb += (size_t)NROWS * 4;
    unsigned int* flagCount = (unsigned int*)wsb;

    hipMemsetAsync(d_out, 0, (size_t)out_size * sizeof(float), stream);
    hipMemsetAsync(flagCount, 0, 4, stream);

    split_kernel<<<(BATCH * NPTS * 32) / 256, 256, 0, stream>>>(f0, Aext);
    split_kernel<<<(BATCH * NPTS * 32) / 256, 256, 0, stream>>>(f1, Bext);
    y2_kernel<<<NROWS / 4, 256, 0, stream>>>(f1, y2);
    gemm_mfma<<<dim3(NPTS / 128, NPTS / 128, BATCH), 256, 0, stream>>>(Aext, Bext, y2, pv1, pv2, pidx);
    resolve_kernel<<<NROWS / 256, 256, 0, stream>>>(pv1, pv2, pidx, idxFinal, bestval, flagList, flagCount);
    recheck_kernel<<<1024, 256, 0, stream>>>(f0, f1, pv1, pv2, pidx, bestval, flagList, flagCount, idxFinal);
    scatter_kernel<<<NROWS / 256, 256, 0, stream>>>(idxFinal, out);
}